// Round 6
// baseline (313.127 us; speedup 1.0000x reference)
//
#include <hip/hip_runtime.h>
#include <stdint.h>

typedef unsigned short u16;
typedef __bf16 bf16_t;
typedef __bf16 bf16x4 __attribute__((ext_vector_type(4)));
typedef __bf16 bf16x8 __attribute__((ext_vector_type(8)));
typedef float f32x4 __attribute__((ext_vector_type(4)));

#define LOG2E 1.4426950408889634f

__device__ __forceinline__ u16 f2bf(float f) {
    union { float f; unsigned int u; } v; v.f = f;
    unsigned int r = v.u + 0x7fffu + ((v.u >> 16) & 1u);
    return (u16)(r >> 16);
}

__device__ __forceinline__ bf16x8 ld8f_bf(const float* __restrict__ p) {
    float4 a = *reinterpret_cast<const float4*>(p);
    float4 b = *reinterpret_cast<const float4*>(p + 4);
    bf16x8 r;
    r[0] = (bf16_t)a.x; r[1] = (bf16_t)a.y; r[2] = (bf16_t)a.z; r[3] = (bf16_t)a.w;
    r[4] = (bf16_t)b.x; r[5] = (bf16_t)b.y; r[6] = (bf16_t)b.z; r[7] = (bf16_t)b.w;
    return r;
}

// ---------------------------------------------------------------------------
// Kernel 1: x[B,C,N] fp32 -> xT[B,N,C] bf16  (xT staged in d_out's 32 MiB)
// ---------------------------------------------------------------------------
__global__ __launch_bounds__(256) void k_transpose(const float* __restrict__ x,
                                                   u16* __restrict__ xT) {
    __shared__ u16 tile[64][68];
    int blk = blockIdx.x;
    int b = blk >> 8;
    int r = blk & 255;
    int c0 = (r & 3) * 64;
    int n0 = (r >> 2) * 64;
    const float* xb = x + (size_t)b * 256 * 4096;
    u16* xTb = xT + (size_t)b * 4096 * 256;
    int t = threadIdx.x;
    int lc = t >> 4;
    int l4 = (t & 15) * 4;
    #pragma unroll
    for (int p = 0; p < 4; ++p) {
        int c = lc + p * 16;
        float4 v = *reinterpret_cast<const float4*>(xb + (size_t)(c0 + c) * 4096 + n0 + l4);
        tile[c][l4 + 0] = f2bf(v.x); tile[c][l4 + 1] = f2bf(v.y);
        tile[c][l4 + 2] = f2bf(v.z); tile[c][l4 + 3] = f2bf(v.w);
    }
    __syncthreads();
    #pragma unroll
    for (int p = 0; p < 4; ++p) {
        int n = lc + p * 16;
        ushort4 v;
        v.x = tile[l4 + 0][n]; v.y = tile[l4 + 1][n];
        v.z = tile[l4 + 2][n]; v.w = tile[l4 + 3][n];
        *reinterpret_cast<ushort4*>(xTb + (size_t)(n0 + n) * 256 + c0 + l4) = v;
    }
}

// ---------------------------------------------------------------------------
// Kernel 2: q/k projection (unchanged)
// ---------------------------------------------------------------------------
__global__ __launch_bounds__(256) void k_proj_qk(
    const u16* __restrict__ xT, const float* __restrict__ Wq, const float* __restrict__ bq,
    const float* __restrict__ Wk, const float* __restrict__ bk,
    u16* __restrict__ qt, u16* __restrict__ kt) {
    int blk = blockIdx.x;
    int b = blk & 7;
    int n0 = (blk >> 3) * 64;
    int t = threadIdx.x;
    int w = t >> 6;
    int lane = t & 63;
    int lo = lane & 15;
    int q = lane >> 4;
    const u16* xTb = xT + (size_t)b * 4096 * 256;
    f32x4 acc[4] = {};
    int nrow = n0 + w * 16 + lo;
    for (int c0 = 0; c0 < 256; c0 += 32) {
        bf16x8 a = *reinterpret_cast<const bf16x8*>(xTb + (size_t)nrow * 256 + c0 + q * 8);
        #pragma unroll
        for (int ot = 0; ot < 4; ++ot) {
            const float* Wp = (ot < 2) ? (Wq + (size_t)(ot * 16 + lo) * 256)
                                       : (Wk + (size_t)((ot - 2) * 16 + lo) * 256);
            bf16x8 bb = ld8f_bf(Wp + c0 + q * 8);
            acc[ot] = __builtin_amdgcn_mfma_f32_16x16x32_bf16(a, bb, acc[ot], 0, 0, 0);
        }
    }
    #pragma unroll
    for (int ot = 0; ot < 4; ++ot) {
        float bias = (ot < 2) ? bq[ot * 16 + lo] : bk[(ot - 2) * 16 + lo];
        #pragma unroll
        for (int r = 0; r < 4; ++r) {
            int n = n0 + w * 16 + q * 4 + r;
            float val = acc[ot][r] + bias;
            if (ot < 2) qt[((size_t)b * 4096 + n) * 32 + ot * 16 + lo] = f2bf(val);
            else        kt[((size_t)b * 4096 + n) * 32 + (ot - 2) * 16 + lo] = f2bf(val);
        }
    }
}

// ---------------------------------------------------------------------------
// Kernel 3: v projection into vn[b][co][n] (unchanged)
// ---------------------------------------------------------------------------
__global__ __launch_bounds__(256) void k_proj_v(
    const u16* __restrict__ xT, const float* __restrict__ Wv, const float* __restrict__ bv,
    u16* __restrict__ vn) {
    int blk = blockIdx.x;
    int b = blk & 7;
    int r2 = blk >> 3;
    int co0 = (r2 & 3) * 64;
    int n0 = (r2 >> 2) * 64;
    int t = threadIdx.x;
    int w = t >> 6;
    int lane = t & 63;
    int lo = lane & 15;
    int q = lane >> 4;
    const u16* xTb = xT + (size_t)b * 4096 * 256;
    f32x4 acc[4] = {};
    int corow = co0 + w * 16 + lo;
    for (int c0 = 0; c0 < 256; c0 += 32) {
        bf16x8 a = ld8f_bf(Wv + (size_t)corow * 256 + c0 + q * 8);
        #pragma unroll
        for (int nt = 0; nt < 4; ++nt) {
            bf16x8 bb = *reinterpret_cast<const bf16x8*>(
                xTb + (size_t)(n0 + nt * 16 + lo) * 256 + c0 + q * 8);
            acc[nt] = __builtin_amdgcn_mfma_f32_16x16x32_bf16(a, bb, acc[nt], 0, 0, 0);
        }
    }
    #pragma unroll
    for (int nt = 0; nt < 4; ++nt) {
        #pragma unroll
        for (int r = 0; r < 4; ++r) {
            int co = co0 + w * 16 + q * 4 + r;
            float val = acc[nt][r] + bv[co];
            vn[((size_t)b * 256 + co) * 4096 + n0 + nt * 16 + lo] = f2bf(val);
        }
    }
}

// ---------------------------------------------------------------------------
// Kernel 4 (v3): flash attention, Q_T=64 x C_T=256 tile, double-buffered E,
// one barrier per 64-key step.
// grid 512 = 8 b (XCD swizzle) * 64 q-tiles(64). 4 waves.
//  A(s): wave w computes E for ALL 64 queries x ITS 16 keys (w*16..w*16+15):
//        1 K-frag load/step, 4 QK MFMAs vs 4 resident q-frags, 16 exps,
//        4 ds_write_b64 into Ebuf[s&1]. K loaded exactly once per block.
//  B(s): wave w owns channels w*64..w*64+63: 8 global V b128 loads,
//        8 ds_read_b128 from Ebuf[s&1], 32 PV MFMAs.
//  Iter s does A(s+1) + B(s), single barrier at end (2 E buffers).
// Shift-free softmax (|S|<~40, exp2 safe; softmax shift-invariant).
// l: per-lane partials -> quad shfl reduce -> cross-wave LDS sum at end.
// ---------------------------------------------------------------------------
__global__ __launch_bounds__(256, 2) void k_flash(
    const u16* __restrict__ qt, const u16* __restrict__ kt,
    const u16* __restrict__ vn, const float* __restrict__ x,
    const float* __restrict__ gamma, float* __restrict__ out) {
    __shared__ bf16_t E_lds[2][64 * 72];
    __shared__ float l_part[4][64];
    int blk = blockIdx.x;
    int b = blk & 7;                 // XCD-swizzle: one batch per XCD
    int m0 = (blk >> 3) * 64;
    int t = threadIdx.x;
    int w = t >> 6;
    int lane = t & 63;
    int lo = lane & 15;
    int q = lane >> 4;
    const u16* qtb = qt + (size_t)b * 4096 * 32;
    const u16* ktb = kt + (size_t)b * 4096 * 32;
    const u16* vb = vn + (size_t)b * 256 * 4096;
    const f32x4 zero = {0.f, 0.f, 0.f, 0.f};

    // resident q-frags: all 64 queries of this block's tile
    bf16x8 qfrag[4];
    #pragma unroll
    for (int qm = 0; qm < 4; ++qm)
        qfrag[qm] = *reinterpret_cast<const bf16x8*>(
            qtb + (size_t)(m0 + qm * 16 + lo) * 32 + q * 8);

    f32x4 O[4][4];
    #pragma unroll
    for (int ct = 0; ct < 4; ++ct)
        #pragma unroll
        for (int mt = 0; mt < 4; ++mt) O[ct][mt] = zero;
    float lsum[4] = {0.f, 0.f, 0.f, 0.f};

    int cw = w * 64;                                       // phase-B channel base
    const u16* kptr = ktb + (size_t)(w * 16 + lo) * 32 + q * 8;  // this wave's K lane ptr

    // ---- A(0) into buffer 0 ----
    {
        bf16x8 kf = *reinterpret_cast<const bf16x8*>(kptr);
        #pragma unroll
        for (int qm = 0; qm < 4; ++qm) {
            f32x4 St = __builtin_amdgcn_mfma_f32_16x16x32_bf16(kf, qfrag[qm], zero, 0, 0, 0);
            bf16x4 pp;
            #pragma unroll
            for (int r = 0; r < 4; ++r) {
                float p = __builtin_amdgcn_exp2f(St[r] * LOG2E);
                lsum[qm] += p;
                pp[r] = (bf16_t)p;
            }
            *reinterpret_cast<bf16x4*>(&E_lds[0][(qm * 16 + lo) * 72 + w * 16 + q * 4]) = pp;
        }
    }
    __syncthreads();

    for (int s = 0; s < 64; ++s) {
        int n0 = s * 64;
        const bf16_t* Er = E_lds[s & 1];
        bf16_t* Ew = E_lds[(s + 1) & 1];
        // ---- A(s+1) ----
        if (s + 1 < 64) {
            bf16x8 kf = *reinterpret_cast<const bf16x8*>(kptr + (size_t)(n0 + 64) * 32);
            #pragma unroll
            for (int qm = 0; qm < 4; ++qm) {
                f32x4 St = __builtin_amdgcn_mfma_f32_16x16x32_bf16(kf, qfrag[qm], zero, 0, 0, 0);
                bf16x4 pp;
                #pragma unroll
                for (int r = 0; r < 4; ++r) {
                    float p = __builtin_amdgcn_exp2f(St[r] * LOG2E);
                    lsum[qm] += p;
                    pp[r] = (bf16_t)p;
                }
                *reinterpret_cast<bf16x4*>(&Ew[(qm * 16 + lo) * 72 + w * 16 + q * 4]) = pp;
            }
        }
        // ---- B(s) ----
        #pragma unroll
        for (int kk = 0; kk < 2; ++kk) {
            bf16x8 vf[4];
            #pragma unroll
            for (int ct = 0; ct < 4; ++ct)
                vf[ct] = *reinterpret_cast<const bf16x8*>(
                    vb + (size_t)(cw + ct * 16 + lo) * 4096 + n0 + kk * 32 + q * 8);
            #pragma unroll
            for (int mt = 0; mt < 4; ++mt) {
                bf16x8 pf = *reinterpret_cast<const bf16x8*>(
                    &Er[(mt * 16 + lo) * 72 + kk * 32 + q * 8]);
                #pragma unroll
                for (int ct = 0; ct < 4; ++ct)
                    O[ct][mt] = __builtin_amdgcn_mfma_f32_16x16x32_bf16(
                        vf[ct], pf, O[ct][mt], 0, 0, 0);
            }
        }
        __syncthreads();
    }

    // ---- l: reduce quads, then across waves via LDS ----
    #pragma unroll
    for (int qm = 0; qm < 4; ++qm) {
        lsum[qm] += __shfl_xor(lsum[qm], 16, 64);
        lsum[qm] += __shfl_xor(lsum[qm], 32, 64);
    }
    if (q == 0) {
        #pragma unroll
        for (int qm = 0; qm < 4; ++qm) l_part[w][qm * 16 + lo] = lsum[qm];
    }
    __syncthreads();
    float linv[4];
    #pragma unroll
    for (int mt = 0; mt < 4; ++mt) {
        int qq = mt * 16 + lo;
        linv[mt] = 1.0f / (l_part[0][qq] + l_part[1][qq] + l_part[2][qq] + l_part[3][qq]);
    }

    float g = gamma[0];
    const float* xb = x + (size_t)b * 256 * 4096;
    float* ob = out + (size_t)b * 256 * 4096;
    #pragma unroll
    for (int ct = 0; ct < 4; ++ct) {
        #pragma unroll
        for (int mt = 0; mt < 4; ++mt) {
            int m = m0 + mt * 16 + lo;
            #pragma unroll
            for (int r = 0; r < 4; ++r) {
                int c = cw + ct * 16 + q * 4 + r;
                size_t idx = (size_t)c * 4096 + m;
                ob[idx] = g * (O[ct][mt][r] * linv[mt]) + xb[idx];
            }
        }
    }
}

// ---------------------------------------------------------------------------
// fp32 I/O. Internal pipeline bf16. Workspace: qt 2 + kt 2 + vn 16 = 20 MiB.
// xT (bf16, 16 MiB) staged inside fp32 d_out (32 MiB); dead before k_flash.
// ---------------------------------------------------------------------------
extern "C" void kernel_launch(void* const* d_in, const int* in_sizes, int n_in,
                              void* d_out, int out_size, void* d_ws, size_t ws_size,
                              hipStream_t stream) {
    const float* x     = (const float*)d_in[0];
    const float* Wq    = (const float*)d_in[1];
    const float* bq    = (const float*)d_in[2];
    const float* Wk    = (const float*)d_in[3];
    const float* bk    = (const float*)d_in[4];
    const float* Wv    = (const float*)d_in[5];
    const float* bv    = (const float*)d_in[6];
    const float* gamma = (const float*)d_in[7];
    float* out = (float*)d_out;

    char* ws = (char*)d_ws;
    u16* xT = (u16*)d_out;                        // 16 MiB bf16 scratch in fp32 d_out
    u16* qt = (u16*)ws;                           //  2 MiB [B,N,32]
    u16* kt = (u16*)(ws + 2097152);               //  2 MiB [B,N,32]
    u16* vn = (u16*)(ws + 2 * 2097152);           // 16 MiB [B,C,N]

    k_transpose<<<2048, 256, 0, stream>>>(x, xT);
    k_proj_qk<<<512, 256, 0, stream>>>(xT, Wq, bq, Wk, bk, qt, kt);
    k_proj_v<<<2048, 256, 0, stream>>>(xT, Wv, bv, vn);
    k_flash<<<512, 256, 0, stream>>>(qt, kt, vn, x, gamma, out);
}

// Round 7
// 268.051 us; speedup vs baseline: 1.1682x; 1.1682x over previous
//
#include <hip/hip_runtime.h>
#include <stdint.h>

typedef unsigned short u16;
typedef __bf16 bf16_t;
typedef __bf16 bf16x4 __attribute__((ext_vector_type(4)));
typedef __bf16 bf16x8 __attribute__((ext_vector_type(8)));
typedef float f32x4 __attribute__((ext_vector_type(4)));

#define LOG2E 1.4426950408889634f

__device__ __forceinline__ u16 f2bf(float f) {
    union { float f; unsigned int u; } v; v.f = f;
    unsigned int r = v.u + 0x7fffu + ((v.u >> 16) & 1u);
    return (u16)(r >> 16);
}

__device__ __forceinline__ bf16x8 ld8f_bf(const float* __restrict__ p) {
    float4 a = *reinterpret_cast<const float4*>(p);
    float4 b = *reinterpret_cast<const float4*>(p + 4);
    bf16x8 r;
    r[0] = (bf16_t)a.x; r[1] = (bf16_t)a.y; r[2] = (bf16_t)a.z; r[3] = (bf16_t)a.w;
    r[4] = (bf16_t)b.x; r[5] = (bf16_t)b.y; r[6] = (bf16_t)b.z; r[7] = (bf16_t)b.w;
    return r;
}

// ---------------------------------------------------------------------------
// Kernel 1: x[B,C,N] fp32 -> xT[B,N,C] bf16  (xT staged in d_out's 32 MiB)
// ---------------------------------------------------------------------------
__global__ __launch_bounds__(256) void k_transpose(const float* __restrict__ x,
                                                   u16* __restrict__ xT) {
    __shared__ u16 tile[64][68];
    int blk = blockIdx.x;
    int b = blk >> 8;
    int r = blk & 255;
    int c0 = (r & 3) * 64;
    int n0 = (r >> 2) * 64;
    const float* xb = x + (size_t)b * 256 * 4096;
    u16* xTb = xT + (size_t)b * 4096 * 256;
    int t = threadIdx.x;
    int lc = t >> 4;
    int l4 = (t & 15) * 4;
    #pragma unroll
    for (int p = 0; p < 4; ++p) {
        int c = lc + p * 16;
        float4 v = *reinterpret_cast<const float4*>(xb + (size_t)(c0 + c) * 4096 + n0 + l4);
        tile[c][l4 + 0] = f2bf(v.x); tile[c][l4 + 1] = f2bf(v.y);
        tile[c][l4 + 2] = f2bf(v.z); tile[c][l4 + 3] = f2bf(v.w);
    }
    __syncthreads();
    #pragma unroll
    for (int p = 0; p < 4; ++p) {
        int n = lc + p * 16;
        ushort4 v;
        v.x = tile[l4 + 0][n]; v.y = tile[l4 + 1][n];
        v.z = tile[l4 + 2][n]; v.w = tile[l4 + 3][n];
        *reinterpret_cast<ushort4*>(xTb + (size_t)(n0 + n) * 256 + c0 + l4) = v;
    }
}

// ---------------------------------------------------------------------------
// Kernel 2 (NEW, fused q/k/v projection): one LDS-staged pass over xT.
// grid 512 = 8 b * 64 n-slabs(64). Block stages its 64x256 xT slab (32 KB)
// into LDS with granule XOR-swizzle (g ^= n&7): every ds_read_b128 fragment
// read spreads 64 lanes uniformly over 32 banks (8-phase floor).
//  - Q/K: wave w owns n-rows w*16..+15: A-frag from LDS, W-frags global
//    (W tiles are small and L2/L1-resident). acc D[m=n][col=o].
//  - V:   wave w owns channels w*64..+63: A-frags = Wv rows (global),
//    B-frags from LDS. acc D[m=co][col=n] -> natural vn[c][n] layout.
// Replaces the two gather-bound projection kernels (fragment loads were
// 64-cache-line global gathers; now LDS reads).
// ---------------------------------------------------------------------------
__global__ __launch_bounds__(256, 2) void k_proj(
    const u16* __restrict__ xT,
    const float* __restrict__ Wq, const float* __restrict__ bq,
    const float* __restrict__ Wk, const float* __restrict__ bk,
    const float* __restrict__ Wv, const float* __restrict__ bv,
    u16* __restrict__ qt, u16* __restrict__ kt, u16* __restrict__ vn) {
    __shared__ u16 Xs[64 * 256];   // 32 KB, granule-swizzled [n][c]
    int blk = blockIdx.x;
    int b = blk & 7;
    int n0 = (blk >> 3) * 64;
    int t = threadIdx.x;
    int w = t >> 6;
    int lane = t & 63;
    int lo = lane & 15;
    int q = lane >> 4;
    const u16* xTb = xT + (size_t)b * 4096 * 256;

    // stage slab: coalesced 16B/lane, granule g swizzled by row
    #pragma unroll
    for (int p = 0; p < 8; ++p) {
        int G = p * 256 + t;
        int n = G >> 5, g = G & 31;
        bf16x8 v = *reinterpret_cast<const bf16x8*>(
            xTb + (size_t)(n0 + n) * 256 + g * 8);
        *reinterpret_cast<bf16x8*>(&Xs[(n * 32 + (g ^ (n & 7))) * 8]) = v;
    }
    __syncthreads();

    f32x4 accqk[4] = {};       // 2 q-tiles + 2 k-tiles
    f32x4 accv[16];            // 4 ct x 4 nt
    #pragma unroll
    for (int i = 0; i < 16; ++i) accv[i] = f32x4{0.f, 0.f, 0.f, 0.f};

    int rowA = w * 16 + lo;    // QK A-frag row (this wave's queries)
    int cw = w * 64;           // V channel base
    for (int c0 = 0; c0 < 256; c0 += 32) {
        int K = c0 >> 3;
        bf16x8 a = *reinterpret_cast<const bf16x8*>(
            &Xs[(rowA * 32 + ((K + q) ^ (lo & 7))) * 8]);
        #pragma unroll
        for (int ot = 0; ot < 4; ++ot) {
            const float* Wp = (ot < 2) ? (Wq + (size_t)(ot * 16 + lo) * 256)
                                       : (Wk + (size_t)((ot - 2) * 16 + lo) * 256);
            bf16x8 bb = ld8f_bf(Wp + c0 + q * 8);
            accqk[ot] = __builtin_amdgcn_mfma_f32_16x16x32_bf16(a, bb, accqk[ot], 0, 0, 0);
        }
        bf16x8 xbf[4];
        #pragma unroll
        for (int nt = 0; nt < 4; ++nt)
            xbf[nt] = *reinterpret_cast<const bf16x8*>(
                &Xs[((nt * 16 + lo) * 32 + ((K + q) ^ (lo & 7))) * 8]);
        #pragma unroll
        for (int ct = 0; ct < 4; ++ct) {
            bf16x8 av = ld8f_bf(Wv + (size_t)(cw + ct * 16 + lo) * 256 + c0 + q * 8);
            #pragma unroll
            for (int nt = 0; nt < 4; ++nt)
                accv[ct * 4 + nt] = __builtin_amdgcn_mfma_f32_16x16x32_bf16(
                    av, xbf[nt], accv[ct * 4 + nt], 0, 0, 0);
        }
    }
    // ---- epilogue: q/k ----
    #pragma unroll
    for (int ot = 0; ot < 4; ++ot) {
        float bias = (ot < 2) ? bq[ot * 16 + lo] : bk[(ot - 2) * 16 + lo];
        #pragma unroll
        for (int r = 0; r < 4; ++r) {
            int n = n0 + w * 16 + q * 4 + r;
            float val = accqk[ot][r] + bias;
            if (ot < 2) qt[((size_t)b * 4096 + n) * 32 + ot * 16 + lo] = f2bf(val);
            else        kt[((size_t)b * 4096 + n) * 32 + (ot - 2) * 16 + lo] = f2bf(val);
        }
    }
    // ---- epilogue: v ----
    #pragma unroll
    for (int ct = 0; ct < 4; ++ct) {
        #pragma unroll
        for (int nt = 0; nt < 4; ++nt) {
            #pragma unroll
            for (int r = 0; r < 4; ++r) {
                int co = cw + ct * 16 + q * 4 + r;
                float val = accv[ct * 4 + nt][r] + bv[co];
                vn[((size_t)b * 256 + co) * 4096 + n0 + nt * 16 + lo] = f2bf(val);
            }
        }
    }
}

// ---------------------------------------------------------------------------
// Kernel 3: flash attention (ROUND-5 PROVEN VERSION, 154 us).
// grid 512 = 8 b (XCD swizzle) * 32 q-blocks(128) * 2 ch-blocks(128).
// ---------------------------------------------------------------------------
__global__ __launch_bounds__(256, 2) void k_flash(
    const u16* __restrict__ qt, const u16* __restrict__ kt,
    const u16* __restrict__ vn, const float* __restrict__ x,
    const float* __restrict__ gamma, float* __restrict__ out) {
    __shared__ bf16_t E_lds[128 * 72];
    __shared__ float l_lds[128];
    int blk = blockIdx.x;
    int b = blk & 7;
    int rest = blk >> 3;
    int m0 = (rest & 31) * 128;
    int ch0 = (rest >> 5) * 128;
    int t = threadIdx.x;
    int w = t >> 6;
    int lane = t & 63;
    int lo = lane & 15;
    int q = lane >> 4;
    const u16* qtb = qt + (size_t)b * 4096 * 32;
    const u16* ktb = kt + (size_t)b * 4096 * 32;
    const u16* vb = vn + (size_t)b * 256 * 4096;

    int qw0 = m0 + w * 32;
    int cw0 = ch0 + w * 32;

    bf16x8 qfrag[2];
    #pragma unroll
    for (int qm = 0; qm < 2; ++qm)
        qfrag[qm] = *reinterpret_cast<const bf16x8*>(
            qtb + (size_t)(qw0 + qm * 16 + lo) * 32 + q * 8);

    f32x4 O[2][8];
    #pragma unroll
    for (int ct = 0; ct < 2; ++ct)
        #pragma unroll
        for (int mt = 0; mt < 8; ++mt) O[ct][mt] = f32x4{0.f, 0.f, 0.f, 0.f};
    float lsum[2] = {0.f, 0.f};
    const f32x4 zero = {0.f, 0.f, 0.f, 0.f};

    for (int n0 = 0; n0 < 4096; n0 += 64) {
        bf16x8 kf[4];
        #pragma unroll
        for (int nt = 0; nt < 4; ++nt)
            kf[nt] = *reinterpret_cast<const bf16x8*>(
                ktb + (size_t)(n0 + nt * 16 + lo) * 32 + q * 8);
        #pragma unroll
        for (int qm = 0; qm < 2; ++qm) {
            #pragma unroll
            for (int nt = 0; nt < 4; ++nt) {
                f32x4 St = __builtin_amdgcn_mfma_f32_16x16x32_bf16(
                    kf[nt], qfrag[qm], zero, 0, 0, 0);
                bf16x4 pp;
                #pragma unroll
                for (int r = 0; r < 4; ++r) {
                    float p = __builtin_amdgcn_exp2f(St[r] * LOG2E);
                    lsum[qm] += p;
                    pp[r] = (bf16_t)p;
                }
                *reinterpret_cast<bf16x4*>(
                    E_lds + (qw0 - m0 + qm * 16 + lo) * 72 + nt * 16 + q * 4) = pp;
            }
        }
        __syncthreads();
        #pragma unroll
        for (int kk = 0; kk < 2; ++kk) {
            bf16x8 vf[2];
            #pragma unroll
            for (int ct = 0; ct < 2; ++ct)
                vf[ct] = *reinterpret_cast<const bf16x8*>(
                    vb + (size_t)(cw0 + ct * 16 + lo) * 4096 + n0 + kk * 32 + q * 8);
            #pragma unroll
            for (int mt = 0; mt < 8; ++mt) {
                bf16x8 pf = *reinterpret_cast<const bf16x8*>(
                    E_lds + (mt * 16 + lo) * 72 + kk * 32 + q * 8);
                #pragma unroll
                for (int ct = 0; ct < 2; ++ct)
                    O[ct][mt] = __builtin_amdgcn_mfma_f32_16x16x32_bf16(
                        vf[ct], pf, O[ct][mt], 0, 0, 0);
            }
        }
        __syncthreads();
    }

    #pragma unroll
    for (int qm = 0; qm < 2; ++qm) {
        lsum[qm] += __shfl_xor(lsum[qm], 16, 64);
        lsum[qm] += __shfl_xor(lsum[qm], 32, 64);
        if (q == 0) l_lds[qw0 - m0 + qm * 16 + lo] = lsum[qm];
    }
    __syncthreads();

    float g = gamma[0];
    const float* xb = x + (size_t)b * 256 * 4096;
    float* ob = out + (size_t)b * 256 * 4096;
    float linv[8];
    #pragma unroll
    for (int mt = 0; mt < 8; ++mt) linv[mt] = 1.0f / l_lds[mt * 16 + lo];
    #pragma unroll
    for (int ct = 0; ct < 2; ++ct) {
        #pragma unroll
        for (int mt = 0; mt < 8; ++mt) {
            int m = m0 + mt * 16 + lo;
            #pragma unroll
            for (int r = 0; r < 4; ++r) {
                int c = cw0 + ct * 16 + q * 4 + r;
                size_t idx = (size_t)c * 4096 + m;
                ob[idx] = g * (O[ct][mt][r] * linv[mt]) + xb[idx];
            }
        }
    }
}

// ---------------------------------------------------------------------------
// fp32 I/O. Internal bf16. Workspace: qt 2 + kt 2 + vn 16 = 20 MiB.
// xT (bf16, 16 MiB) staged inside fp32 d_out (32 MiB); dead before k_flash.
// ---------------------------------------------------------------------------
extern "C" void kernel_launch(void* const* d_in, const int* in_sizes, int n_in,
                              void* d_out, int out_size, void* d_ws, size_t ws_size,
                              hipStream_t stream) {
    const float* x     = (const float*)d_in[0];
    const float* Wq    = (const float*)d_in[1];
    const float* bq    = (const float*)d_in[2];
    const float* Wk    = (const float*)d_in[3];
    const float* bk    = (const float*)d_in[4];
    const float* Wv    = (const float*)d_in[5];
    const float* bv    = (const float*)d_in[6];
    const float* gamma = (const float*)d_in[7];
    float* out = (float*)d_out;

    char* ws = (char*)d_ws;
    u16* xT = (u16*)d_out;                        // 16 MiB bf16 scratch in fp32 d_out
    u16* qt = (u16*)ws;                           //  2 MiB [B,N,32]
    u16* kt = (u16*)(ws + 2097152);               //  2 MiB [B,N,32]
    u16* vn = (u16*)(ws + 2 * 2097152);           // 16 MiB [B,C,N]

    k_transpose<<<2048, 256, 0, stream>>>(x, xT);
    k_proj<<<512, 256, 0, stream>>>(xT, Wq, bq, Wk, bk, Wv, bv, qt, kt, vn);
    k_flash<<<512, 256, 0, stream>>>(qt, kt, vn, x, gamma, out);
}

// Round 8
// 238.218 us; speedup vs baseline: 1.3145x; 1.1252x over previous
//
#include <hip/hip_runtime.h>
#include <stdint.h>

typedef unsigned short u16;
typedef __bf16 bf16_t;
typedef __bf16 bf16x4 __attribute__((ext_vector_type(4)));
typedef __bf16 bf16x8 __attribute__((ext_vector_type(8)));
typedef float f32x4 __attribute__((ext_vector_type(4)));

#define LOG2E 1.4426950408889634f

__device__ __forceinline__ u16 f2bf(float f) {
    union { float f; unsigned int u; } v; v.f = f;
    unsigned int r = v.u + 0x7fffu + ((v.u >> 16) & 1u);
    return (u16)(r >> 16);
}

__device__ __forceinline__ bf16x8 ld8f_bf(const float* __restrict__ p) {
    float4 a = *reinterpret_cast<const float4*>(p);
    float4 b = *reinterpret_cast<const float4*>(p + 4);
    bf16x8 r;
    r[0] = (bf16_t)a.x; r[1] = (bf16_t)a.y; r[2] = (bf16_t)a.z; r[3] = (bf16_t)a.w;
    r[4] = (bf16_t)b.x; r[5] = (bf16_t)b.y; r[6] = (bf16_t)b.z; r[7] = (bf16_t)b.w;
    return r;
}

// ---------------------------------------------------------------------------
// Kernel 1: x[B,C,N] fp32 -> xT[B,N,C] bf16  (xT staged in d_out's 32 MiB)
// ---------------------------------------------------------------------------
__global__ __launch_bounds__(256) void k_transpose(const float* __restrict__ x,
                                                   u16* __restrict__ xT) {
    __shared__ u16 tile[64][68];
    int blk = blockIdx.x;
    int b = blk >> 8;
    int r = blk & 255;
    int c0 = (r & 3) * 64;
    int n0 = (r >> 2) * 64;
    const float* xb = x + (size_t)b * 256 * 4096;
    u16* xTb = xT + (size_t)b * 4096 * 256;
    int t = threadIdx.x;
    int lc = t >> 4;
    int l4 = (t & 15) * 4;
    #pragma unroll
    for (int p = 0; p < 4; ++p) {
        int c = lc + p * 16;
        float4 v = *reinterpret_cast<const float4*>(xb + (size_t)(c0 + c) * 4096 + n0 + l4);
        tile[c][l4 + 0] = f2bf(v.x); tile[c][l4 + 1] = f2bf(v.y);
        tile[c][l4 + 2] = f2bf(v.z); tile[c][l4 + 3] = f2bf(v.w);
    }
    __syncthreads();
    #pragma unroll
    for (int p = 0; p < 4; ++p) {
        int n = lc + p * 16;
        ushort4 v;
        v.x = tile[l4 + 0][n]; v.y = tile[l4 + 1][n];
        v.z = tile[l4 + 2][n]; v.w = tile[l4 + 3][n];
        *reinterpret_cast<ushort4*>(xTb + (size_t)(n0 + n) * 256 + c0 + l4) = v;
    }
}

// ---------------------------------------------------------------------------
// Kernel 2 (v3): fused q/k/v projection, ALL operands LDS-staged (no global
// gathers feeding MFMAs). grid 512 = 8 b * 64 n-slabs(64).
// LDS: Xs 32KB (xT slab, granule-swizzled) + Ws 32KB (Wq||Wk bf16, swizzled,
// staged once) + Wvs 16KB (per-c0 [256co x 32c] slice, swizzled) = 80KB
// -> 2 blocks/CU. All staging loads are coalesced; frag reads hit the
// 8-phase LDS floor.
// ---------------------------------------------------------------------------
__global__ __launch_bounds__(256, 2) void k_proj(
    const u16* __restrict__ xT,
    const float* __restrict__ Wq, const float* __restrict__ bq,
    const float* __restrict__ Wk, const float* __restrict__ bk,
    const float* __restrict__ Wv, const float* __restrict__ bv,
    u16* __restrict__ qt, u16* __restrict__ kt, u16* __restrict__ vn) {
    __shared__ u16 Xs[64 * 256];    // [n][c] granules swizzled by n&7
    __shared__ u16 Ws[64 * 256];    // rows 0-31 Wq, 32-63 Wk; swizzle row&7
    __shared__ u16 Wvs[256 * 32];   // [co][c-slice] granules swizzled by co&3
    int blk = blockIdx.x;
    int b = blk & 7;
    int n0 = (blk >> 3) * 64;
    int t = threadIdx.x;
    int w = t >> 6;
    int lane = t & 63;
    int lo = lane & 15;
    int q = lane >> 4;
    const u16* xTb = xT + (size_t)b * 4096 * 256;

    // ---- stage Xs (bf16 copy) and Ws (fp32->bf16), coalesced ----
    #pragma unroll
    for (int p = 0; p < 8; ++p) {
        int G = p * 256 + t;
        int n = G >> 5, g = G & 31;
        bf16x8 v = *reinterpret_cast<const bf16x8*>(
            xTb + (size_t)(n0 + n) * 256 + g * 8);
        *reinterpret_cast<bf16x8*>(&Xs[(n * 32 + (g ^ (n & 7))) * 8]) = v;
        const float* src = (n < 32) ? (Wq + (size_t)n * 256 + g * 8)
                                    : (Wk + (size_t)(n - 32) * 256 + g * 8);
        *reinterpret_cast<bf16x8*>(&Ws[(n * 32 + (g ^ (n & 7))) * 8]) = ld8f_bf(src);
    }

    f32x4 accqk[4] = {};
    f32x4 accv[16];
    #pragma unroll
    for (int i = 0; i < 16; ++i) accv[i] = f32x4{0.f, 0.f, 0.f, 0.f};

    int rowA = w * 16 + lo;
    int cw = w * 64;
    for (int c0 = 0; c0 < 256; c0 += 32) {
        // ---- stage Wv slice [256 co][32 c], coalesced 128B chunks ----
        __syncthreads();   // previous step's Wvs reads done
        #pragma unroll
        for (int p = 0; p < 4; ++p) {
            int G = p * 256 + t;
            int co = G >> 2, g2 = G & 3;
            *reinterpret_cast<bf16x8*>(&Wvs[(co * 4 + (g2 ^ (co & 3))) * 8]) =
                ld8f_bf(Wv + (size_t)co * 256 + c0 + g2 * 8);
        }
        __syncthreads();

        int K = c0 >> 3;
        // ---- QK ----
        bf16x8 a = *reinterpret_cast<const bf16x8*>(
            &Xs[(rowA * 32 + ((K + q) ^ (lo & 7))) * 8]);
        #pragma unroll
        for (int ot = 0; ot < 4; ++ot) {
            bf16x8 bb = *reinterpret_cast<const bf16x8*>(
                &Ws[((ot * 16 + lo) * 32 + ((K + q) ^ (lo & 7))) * 8]);
            accqk[ot] = __builtin_amdgcn_mfma_f32_16x16x32_bf16(a, bb, accqk[ot], 0, 0, 0);
        }
        // ---- V ----
        bf16x8 xbf[4];
        #pragma unroll
        for (int nt = 0; nt < 4; ++nt)
            xbf[nt] = *reinterpret_cast<const bf16x8*>(
                &Xs[((nt * 16 + lo) * 32 + ((K + q) ^ (lo & 7))) * 8]);
        #pragma unroll
        for (int ct = 0; ct < 4; ++ct) {
            int co = cw + ct * 16 + lo;
            bf16x8 av = *reinterpret_cast<const bf16x8*>(
                &Wvs[(co * 4 + (q ^ (co & 3))) * 8]);
            #pragma unroll
            for (int nt = 0; nt < 4; ++nt)
                accv[ct * 4 + nt] = __builtin_amdgcn_mfma_f32_16x16x32_bf16(
                    av, xbf[nt], accv[ct * 4 + nt], 0, 0, 0);
        }
    }
    // ---- epilogue: q/k ----
    #pragma unroll
    for (int ot = 0; ot < 4; ++ot) {
        float bias = (ot < 2) ? bq[ot * 16 + lo] : bk[(ot - 2) * 16 + lo];
        #pragma unroll
        for (int r = 0; r < 4; ++r) {
            int n = n0 + w * 16 + q * 4 + r;
            float val = accqk[ot][r] + bias;
            if (ot < 2) qt[((size_t)b * 4096 + n) * 32 + ot * 16 + lo] = f2bf(val);
            else        kt[((size_t)b * 4096 + n) * 32 + (ot - 2) * 16 + lo] = f2bf(val);
        }
    }
    // ---- epilogue: v ----
    #pragma unroll
    for (int ct = 0; ct < 4; ++ct) {
        #pragma unroll
        for (int nt = 0; nt < 4; ++nt) {
            #pragma unroll
            for (int r = 0; r < 4; ++r) {
                int co = cw + ct * 16 + q * 4 + r;
                float val = accv[ct * 4 + nt][r] + bv[co];
                vn[((size_t)b * 256 + co) * 4096 + n0 + nt * 16 + lo] = f2bf(val);
            }
        }
    }
}

// ---------------------------------------------------------------------------
// Kernel 3 (v4): flash attention, r5 geometry (128q x 128ch, ch-split 2)
// + double-buffered E + ONE barrier per 64-key step.
// Iter s: A(s+1) [K-load, QK MFMA, exp, E-write to buf (s+1)&1] interleaved
// with B(s) [V-load, E-read buf s&1, PV MFMA]; single barrier. Buffer reuse
// is safe: A(s+2) writes buf s&1 only after the iter-s barrier.
// ---------------------------------------------------------------------------
__global__ __launch_bounds__(256, 2) void k_flash(
    const u16* __restrict__ qt, const u16* __restrict__ kt,
    const u16* __restrict__ vn, const float* __restrict__ x,
    const float* __restrict__ gamma, float* __restrict__ out) {
    __shared__ bf16_t E_lds[2][128 * 72];
    __shared__ float l_lds[128];
    int blk = blockIdx.x;
    int b = blk & 7;
    int rest = blk >> 3;
    int m0 = (rest & 31) * 128;
    int ch0 = (rest >> 5) * 128;
    int t = threadIdx.x;
    int w = t >> 6;
    int lane = t & 63;
    int lo = lane & 15;
    int q = lane >> 4;
    const u16* qtb = qt + (size_t)b * 4096 * 32;
    const u16* ktb = kt + (size_t)b * 4096 * 32;
    const u16* vb = vn + (size_t)b * 256 * 4096;

    int qw0 = m0 + w * 32;
    int cw0 = ch0 + w * 32;

    bf16x8 qfrag[2];
    #pragma unroll
    for (int qm = 0; qm < 2; ++qm)
        qfrag[qm] = *reinterpret_cast<const bf16x8*>(
            qtb + (size_t)(qw0 + qm * 16 + lo) * 32 + q * 8);

    f32x4 O[2][8];
    #pragma unroll
    for (int ct = 0; ct < 2; ++ct)
        #pragma unroll
        for (int mt = 0; mt < 8; ++mt) O[ct][mt] = f32x4{0.f, 0.f, 0.f, 0.f};
    float lsum[2] = {0.f, 0.f};
    const f32x4 zero = {0.f, 0.f, 0.f, 0.f};

    // ---- A(0) into buffer 0 ----
    {
        bf16x8 kf[4];
        #pragma unroll
        for (int nt = 0; nt < 4; ++nt)
            kf[nt] = *reinterpret_cast<const bf16x8*>(
                ktb + (size_t)(nt * 16 + lo) * 32 + q * 8);
        #pragma unroll
        for (int qm = 0; qm < 2; ++qm)
            #pragma unroll
            for (int nt = 0; nt < 4; ++nt) {
                f32x4 St = __builtin_amdgcn_mfma_f32_16x16x32_bf16(
                    kf[nt], qfrag[qm], zero, 0, 0, 0);
                bf16x4 pp;
                #pragma unroll
                for (int r = 0; r < 4; ++r) {
                    float p = __builtin_amdgcn_exp2f(St[r] * LOG2E);
                    lsum[qm] += p;
                    pp[r] = (bf16_t)p;
                }
                *reinterpret_cast<bf16x4*>(
                    &E_lds[0][(qw0 - m0 + qm * 16 + lo) * 72 + nt * 16 + q * 4]) = pp;
            }
    }
    __syncthreads();

    for (int s = 0; s < 64; ++s) {
        int n0 = s * 64;
        const bf16_t* Er = E_lds[s & 1];
        bf16_t* Ew = E_lds[(s + 1) & 1];
        // ---- A(s+1) ----
        if (s + 1 < 64) {
            bf16x8 kf[4];
            #pragma unroll
            for (int nt = 0; nt < 4; ++nt)
                kf[nt] = *reinterpret_cast<const bf16x8*>(
                    ktb + (size_t)(n0 + 64 + nt * 16 + lo) * 32 + q * 8);
            #pragma unroll
            for (int qm = 0; qm < 2; ++qm)
                #pragma unroll
                for (int nt = 0; nt < 4; ++nt) {
                    f32x4 St = __builtin_amdgcn_mfma_f32_16x16x32_bf16(
                        kf[nt], qfrag[qm], zero, 0, 0, 0);
                    bf16x4 pp;
                    #pragma unroll
                    for (int r = 0; r < 4; ++r) {
                        float p = __builtin_amdgcn_exp2f(St[r] * LOG2E);
                        lsum[qm] += p;
                        pp[r] = (bf16_t)p;
                    }
                    *reinterpret_cast<bf16x4*>(
                        &Ew[(qw0 - m0 + qm * 16 + lo) * 72 + nt * 16 + q * 4]) = pp;
                }
        }
        // ---- B(s) ----
        #pragma unroll
        for (int kk = 0; kk < 2; ++kk) {
            bf16x8 vf[2];
            #pragma unroll
            for (int ct = 0; ct < 2; ++ct)
                vf[ct] = *reinterpret_cast<const bf16x8*>(
                    vb + (size_t)(cw0 + ct * 16 + lo) * 4096 + n0 + kk * 32 + q * 8);
            #pragma unroll
            for (int mt = 0; mt < 8; ++mt) {
                bf16x8 pf = *reinterpret_cast<const bf16x8*>(
                    &Er[(mt * 16 + lo) * 72 + kk * 32 + q * 8]);
                #pragma unroll
                for (int ct = 0; ct < 2; ++ct)
                    O[ct][mt] = __builtin_amdgcn_mfma_f32_16x16x32_bf16(
                        vf[ct], pf, O[ct][mt], 0, 0, 0);
            }
        }
        __syncthreads();
    }

    #pragma unroll
    for (int qm = 0; qm < 2; ++qm) {
        lsum[qm] += __shfl_xor(lsum[qm], 16, 64);
        lsum[qm] += __shfl_xor(lsum[qm], 32, 64);
        if (q == 0) l_lds[qw0 - m0 + qm * 16 + lo] = lsum[qm];
    }
    __syncthreads();

    float g = gamma[0];
    const float* xb = x + (size_t)b * 256 * 4096;
    float* ob = out + (size_t)b * 256 * 4096;
    float linv[8];
    #pragma unroll
    for (int mt = 0; mt < 8; ++mt) linv[mt] = 1.0f / l_lds[mt * 16 + lo];
    #pragma unroll
    for (int ct = 0; ct < 2; ++ct) {
        #pragma unroll
        for (int mt = 0; mt < 8; ++mt) {
            int m = m0 + mt * 16 + lo;
            #pragma unroll
            for (int r = 0; r < 4; ++r) {
                int c = cw0 + ct * 16 + q * 4 + r;
                size_t idx = (size_t)c * 4096 + m;
                ob[idx] = g * (O[ct][mt][r] * linv[mt]) + xb[idx];
            }
        }
    }
}

// ---------------------------------------------------------------------------
// fp32 I/O. Internal bf16. Workspace: qt 2 + kt 2 + vn 16 = 20 MiB.
// xT (bf16, 16 MiB) staged inside fp32 d_out (32 MiB); dead before k_flash.
// ---------------------------------------------------------------------------
extern "C" void kernel_launch(void* const* d_in, const int* in_sizes, int n_in,
                              void* d_out, int out_size, void* d_ws, size_t ws_size,
                              hipStream_t stream) {
    const float* x     = (const float*)d_in[0];
    const float* Wq    = (const float*)d_in[1];
    const float* bq    = (const float*)d_in[2];
    const float* Wk    = (const float*)d_in[3];
    const float* bk    = (const float*)d_in[4];
    const float* Wv    = (const float*)d_in[5];
    const float* bv    = (const float*)d_in[6];
    const float* gamma = (const float*)d_in[7];
    float* out = (float*)d_out;

    char* ws = (char*)d_ws;
    u16* xT = (u16*)d_out;                        // 16 MiB bf16 scratch in fp32 d_out
    u16* qt = (u16*)ws;                           //  2 MiB [B,N,32]
    u16* kt = (u16*)(ws + 2097152);               //  2 MiB [B,N,32]
    u16* vn = (u16*)(ws + 2 * 2097152);           // 16 MiB [B,C,N]

    k_transpose<<<2048, 256, 0, stream>>>(x, xT);
    k_proj<<<512, 256, 0, stream>>>(xT, Wq, bq, Wk, bk, Wv, bv, qt, kt, vn);
    k_flash<<<512, 256, 0, stream>>>(qt, kt, vn, x, gamma, out);
}